// Round 6
// baseline (2015.304 us; speedup 1.0000x reference)
//
#include <hip/hip_runtime.h>
#include <hip/hip_bf16.h>

#define DEV __device__ __forceinline__

typedef __attribute__((ext_vector_type(8))) short short8;
typedef __attribute__((ext_vector_type(4))) float f32x4;

#define NCHUNK 64    // edge chunks for the bucket multisplit
#define BROWS 64     // target rows per bucket
#define BSH 6        // log2(BROWS)
#define MAXNB 4096   // max buckets per direction (LDS cursor/counter arrays)

DEV unsigned short f2bf(float f) {
    __hip_bfloat16 h = __float2bfloat16(f);
    unsigned short u;
    __builtin_memcpy(&u, &h, 2);
    return u;
}
DEV float bf2f(unsigned short u) { return __uint_as_float((unsigned int)u << 16); }

DEV f32x4 mfma_bf16(short8 a, short8 b, f32x4 c) {
    return __builtin_amdgcn_mfma_f32_16x16x32_bf16(a, b, c, 0, 0, 0);
}

// fp32 -> (hi, lo) bf16 pair; hi+lo represents v to ~2^-17 rel.
DEV void make_hilo(const float* a8, short8& hi, short8& lo) {
    #pragma unroll
    for (int j = 0; j < 8; ++j) {
        const float v = a8[j];
        const unsigned short h = f2bf(v);
        hi[j] = (short)h;
        lo[j] = (short)f2bf(v - bf2f(h));
    }
}

// 3-term split-precision MFMA accumulate against 4 column-frags.
DEV void mfma3(f32x4 acc[4], short8 ah, short8 al,
               const unsigned short* __restrict__ Bh,
               const unsigned short* __restrict__ Bl,
               int nkt, int tidx, int lane) {
    #pragma unroll
    for (int c = 0; c < 4; ++c) {
        const size_t o = ((size_t)(c * nkt + tidx) * 64 + lane) * 8;
        const short8 bh = *(const short8*)(Bh + o);
        const short8 bl = *(const short8*)(Bl + o);
        acc[c] = mfma_bf16(ah, bh, acc[c]);
        acc[c] = mfma_bf16(al, bh, acc[c]);
        acc[c] = mfma_bf16(ah, bl, acc[c]);
    }
}

// XOR-chunk-swizzled fp32 activation buffer (16 rows x 64)
DEV int swf(int row, int col) {
    return row * 64 + ((((col >> 3) ^ row) & 7) << 3) + (col & 7);
}

DEV void gemm_lds(f32x4 acc[4], const float* Xl,
                  const unsigned short* Bh, const unsigned short* Bl,
                  int nkt, int t0, int ntk, int l15, int q, int lane) {
    for (int t = 0; t < ntk; ++t) {
        const int ch = (t * 4 + q) ^ (l15 & 7);
        const float* a8 = Xl + l15 * 64 + ch * 8;
        short8 ah, al;
        make_hilo(a8, ah, al);
        mfma3(acc, ah, al, Bh, Bl, nkt, t0 + t, lane);
    }
}

DEV void gemm_glb(f32x4 acc[4], const float* __restrict__ Xg, int rbase, int N,
                  const unsigned short* Bh, const unsigned short* Bl,
                  int nkt, int t0, int ntk, int l15, int q, int lane) {
    const int grow = rbase + l15;
    const bool ok = grow < N;
    for (int t = 0; t < ntk; ++t) {
        float a8[8];
        if (ok) {
            const float4 v0 = *(const float4*)(Xg + (size_t)grow * 64 + t * 32 + q * 8);
            const float4 v1 = *(const float4*)(Xg + (size_t)grow * 64 + t * 32 + q * 8 + 4);
            a8[0] = v0.x; a8[1] = v0.y; a8[2] = v0.z; a8[3] = v0.w;
            a8[4] = v1.x; a8[5] = v1.y; a8[6] = v1.z; a8[7] = v1.w;
        } else {
            #pragma unroll
            for (int j = 0; j < 8; ++j) a8[j] = 0.f;
        }
        short8 ah, al;
        make_hilo(a8, ah, al);
        mfma3(acc, ah, al, Bh, Bl, nkt, t0 + t, lane);
    }
}

// ---------------------------------------------------------------------------
// Weight prep (unchanged)
// ---------------------------------------------------------------------------
#define NMAT 15
struct PrepArgs {
    const float* src[NMAT];
    unsigned short* hi[NMAT];
    unsigned short* lo[NMAT];
    int nkt[NMAT];
    int KR[NMAT];
};

__global__ __launch_bounds__(256)
void prep_kernel(PrepArgs pa)
{
    const int m = blockIdx.y;
    const int nkt = pa.nkt[m];
    const int nthr = nkt * 4 * 64;
    const int p = blockIdx.x * 256 + threadIdx.x;
    if (p >= nthr) return;
    const int f = p >> 6, l = p & 63;
    const int c = f / nkt, t = f % nkt;
    const int kbase = t * 32 + ((l >> 4) << 3);
    const int n = c * 16 + (l & 15);
    const float* W = pa.src[m];
    const int KR = pa.KR[m];
    unsigned short* ph = pa.hi[m] + (size_t)p * 8;
    unsigned short* pl = pa.lo[m] + (size_t)p * 8;
    #pragma unroll
    for (int j = 0; j < 8; ++j) {
        const int k = kbase + j;
        const float v = (k < KR) ? W[k * 64 + n] : 0.f;
        const unsigned short h = f2bf(v);
        ph[j] = h;
        pl[j] = f2bf(v - bf2f(h));
    }
}

// ---------------------------------------------------------------------------
// R20: 64-row-bucket multisplit replaces the per-key hist/scan/scatter CSR.
// count -> total -> bucket-scan -> chunk-offsets -> coalesced scatter; then
// agg accumulates per-bucket G in LDS (fp32 atomics) directly from the
// sequential bucket stream. pairs/rs/rl/Hp all eliminated.
// ---------------------------------------------------------------------------
__global__ __launch_bounds__(256)
void count_bkt(const int* __restrict__ ei, int E, int chunk_len,
               int nb1, int nb2, int* __restrict__ cnt1, int* __restrict__ cnt2)
{
    __shared__ int lc[MAXNB];
    const int s = blockIdx.x;
    const int d2 = blockIdx.y;
    const int nb = d2 ? nb2 : nb1;
    const int* __restrict__ key = d2 ? (ei + E) : ei;
    int* __restrict__ cnt = (d2 ? cnt2 : cnt1) + (size_t)s * nb;

    for (int i = threadIdx.x; i < nb; i += 256) lc[i] = 0;
    __syncthreads();
    const int e0 = s * chunk_len;
    const int e1 = (e0 + chunk_len < E) ? (e0 + chunk_len) : E;
    const int len = (e1 > e0) ? (e1 - e0) : 0;
    const int tid = threadIdx.x;
    const int nv4 = len >> 2;
    for (int g = tid; g < nv4; g += 256) {
        const int4 kk = *(const int4*)(key + e0 + g * 4);
        atomicAdd(&lc[kk.x >> BSH], 1);
        atomicAdd(&lc[kk.y >> BSH], 1);
        atomicAdd(&lc[kk.z >> BSH], 1);
        atomicAdd(&lc[kk.w >> BSH], 1);
    }
    for (int e = e0 + (nv4 << 2) + tid; e < e1; e += 256)
        atomicAdd(&lc[key[e] >> BSH], 1);
    __syncthreads();
    for (int i = threadIdx.x; i < nb; i += 256) cnt[i] = lc[i];
}

__global__ __launch_bounds__(256)
void total_bkt(const int* __restrict__ cnt1, int nb1, int* __restrict__ tot1,
               const int* __restrict__ cnt2, int nb2, int* __restrict__ tot2)
{
    const int d2 = blockIdx.y;
    const int nb = d2 ? nb2 : nb1;
    const int* __restrict__ cnt = d2 ? cnt2 : cnt1;
    int* __restrict__ tot = d2 ? tot2 : tot1;
    const int b = blockIdx.x * 256 + (int)threadIdx.x;
    if (b >= nb) return;
    int t = 0;
    #pragma unroll
    for (int s = 0; s < NCHUNK; ++s) t += cnt[(size_t)s * nb + b];
    tot[b] = t;
}

// Exclusive scan of tot -> bs (bucket starts); bs[nb] = total.
__global__ __launch_bounds__(256)
void bscan_bkt(const int* __restrict__ tot1, int nb1, int* __restrict__ bs1,
               const int* __restrict__ tot2, int nb2, int* __restrict__ bs2)
{
    __shared__ int wsum[4];
    const int d2 = blockIdx.x;
    const int nb = d2 ? nb2 : nb1;
    const int* __restrict__ tot = d2 ? tot2 : tot1;
    int* __restrict__ bs = d2 ? bs2 : bs1;
    const int t = threadIdx.x, lane = t & 63, wid = t >> 6;
    const int Gc = (nb + 255) / 256;
    const int b0 = t * Gc;
    int sum = 0;
    for (int i = 0; i < Gc; ++i) {
        const int b = b0 + i;
        if (b < nb) sum += tot[b];
    }
    int x = sum;
    #pragma unroll
    for (int d = 1; d < 64; d <<= 1) { int y = __shfl_up(x, d); if (lane >= d) x += y; }
    if (lane == 63) wsum[wid] = x;
    __syncthreads();
    int woff = 0;
    for (int i = 0; i < wid; ++i) woff += wsum[i];
    int run = woff + x - sum;
    for (int i = 0; i < Gc; ++i) {
        const int b = b0 + i;
        if (b < nb) { bs[b] = run; run += tot[b]; }
    }
    if (t == 255) bs[nb] = woff + x;
}

// cnt[s][b] -> absolute write offsets (bucket-major layout, chunks in order).
__global__ __launch_bounds__(256)
void off_bkt(int* __restrict__ cnt1, int nb1, const int* __restrict__ bs1,
             int* __restrict__ cnt2, int nb2, const int* __restrict__ bs2)
{
    const int d2 = blockIdx.y;
    const int nb = d2 ? nb2 : nb1;
    int* __restrict__ cnt = d2 ? cnt2 : cnt1;
    const int* __restrict__ bs = d2 ? bs2 : bs1;
    const int b = blockIdx.x * 256 + (int)threadIdx.x;
    if (b >= nb) return;
    int run = bs[b];
    #pragma unroll
    for (int s = 0; s < NCHUNK; ++s) {
        int* p = cnt + (size_t)s * nb + b;
        const int t = *p;
        *p = run;
        run += t;
    }
}

// Coalesced bucket scatter: items packed (src | tgtlo<<20, en_bits).
// Writes are consecutive-address runs per (chunk,bucket); the open-line set
// (<= nb lines ~ 200KB/block) merges to full lines in L2.
__global__ __launch_bounds__(256)
void scatter_bkt(const int* __restrict__ ei, int E, int chunk_len,
                 const float* __restrict__ ef,
                 const float* __restrict__ eshp, const float* __restrict__ escp,
                 int nb1, int nb2,
                 const int* __restrict__ off1, const int* __restrict__ off2,
                 int2* __restrict__ items1, int2* __restrict__ items2)
{
    __shared__ int cur[MAXNB];
    const int s = blockIdx.x;
    const int d2 = blockIdx.y;
    const int nb = d2 ? nb2 : nb1;
    const int* __restrict__ key = d2 ? (ei + E) : ei;
    const int* __restrict__ oth = d2 ? ei : (ei + E);
    const int* __restrict__ off = (d2 ? off2 : off1) + (size_t)s * nb;
    int2* __restrict__ items = d2 ? items2 : items1;

    for (int i = threadIdx.x; i < nb; i += 256) cur[i] = off[i];
    __syncthreads();
    const float esh = eshp[0], esc = escp[0];
    const int e0 = s * chunk_len;
    const int e1 = (e0 + chunk_len < E) ? (e0 + chunk_len) : E;
    const int len = (e1 > e0) ? (e1 - e0) : 0;
    const int tid = threadIdx.x;
    const int nv4 = len >> 2;
    for (int g = tid; g < nv4; g += 256) {
        const int e4 = e0 + g * 4;
        const int4 kk = *(const int4*)(key + e4);
        const int4 oo = *(const int4*)(oth + e4);
        const float4 ee = *(const float4*)(ef + e4);
        const int ks[4] = {kk.x, kk.y, kk.z, kk.w};
        const int os[4] = {oo.x, oo.y, oo.z, oo.w};
        const float es[4] = {ee.x, ee.y, ee.z, ee.w};
        #pragma unroll
        for (int u = 0; u < 4; ++u) {
            const int slot = atomicAdd(&cur[ks[u] >> BSH], 1);
            items[slot] = make_int2(os[u] | ((ks[u] & (BROWS - 1)) << 20),
                                    __float_as_int((es[u] - esh) * esc));
        }
    }
    for (int e = e0 + (nv4 << 2) + tid; e < e1; e += 256) {
        const int k = key[e];
        const int slot = atomicAdd(&cur[k >> BSH], 1);
        items[slot] = make_int2(oth[e] | ((k & (BROWS - 1)) << 20),
                                __float_as_int((ef[e] - esh) * esc));
    }
}

// ---------------------------------------------------------------------------
// Bucket-fused aggregation: block = bucket of 64 target rows. G[64][64] f32 +
// staged Ttgt in LDS (24.8KB -> 6 blocks/CU, 24 waves). Sequential item
// stream, coalesced 128B src-row gathers, ds_add_f32 accumulation. Emits
// per-row degree (replaces rs for post).
// ---------------------------------------------------------------------------
__global__ __launch_bounds__(256)
void agg_bkt(int N, const int* __restrict__ bs,
             const int2* __restrict__ items,
             const unsigned short* __restrict__ Ttgt,
             const unsigned short* __restrict__ Tsrc,
             const float* __restrict__ We, const float* __restrict__ sfp,
             float* __restrict__ G, int* __restrict__ deg)
{
    __shared__ float Gs[BROWS][64];
    __shared__ unsigned short Ts[BROWS][64];
    __shared__ int ds[BROWS];

    const int b = blockIdx.x;
    const int r0 = b * BROWS;
    const int tid = threadIdx.x;
    const int lane = tid & 63, wv = tid >> 6;

    for (int i = tid; i < BROWS * 64; i += 256) {
        ((float*)Gs)[i] = 0.f;
        const int rr = i >> 6;
        unsigned short tv = 0;
        if (r0 + rr < N) tv = Ttgt[(size_t)(r0 + rr) * 64 + (i & 63)];
        ((unsigned short*)Ts)[i] = tv;
    }
    for (int i = tid; i < BROWS; i += 256) ds[i] = 0;
    __syncthreads();

    const float sfWe = sfp[0] * We[lane];
    const int ibeg = bs[b], iend = bs[b + 1];
    const int cnt = iend - ibeg;
    const int per = (cnt + 3) >> 2;
    int p = ibeg + wv * per;
    const int pe = (p + per < iend) ? (p + per) : iend;

    for (; p + 8 <= pe; p += 8) {
        const int2 it = items[p + (lane & 7)];
        int srcs[8], tls[8];
        float ens[8];
        #pragma unroll
        for (int u = 0; u < 8; ++u) {
            const int xi = __shfl(it.x, u, 8);
            const int yi = __shfl(it.y, u, 8);
            srcs[u] = xi & 0xFFFFF;
            tls[u] = xi >> 20;
            ens[u] = __int_as_float(yi);
        }
        float bv[8];
        #pragma unroll
        for (int u = 0; u < 8; ++u)
            bv[u] = bf2f(Tsrc[(size_t)srcs[u] * 64 + lane]);
        #pragma unroll
        for (int u = 0; u < 8; ++u) {
            const float m = fmaxf(bf2f(Ts[tls[u]][lane]) + bv[u] + ens[u] * sfWe, 0.f);
            atomicAdd(&Gs[tls[u]][lane], m);
        }
        if (lane == 0) {
            #pragma unroll
            for (int u = 0; u < 8; ++u) atomicAdd(&ds[tls[u]], 1);
        }
    }
    for (; p < pe; ++p) {
        const int2 it = items[p];
        const int src = it.x & 0xFFFFF;
        const int tl = it.x >> 20;
        const float bv = bf2f(Tsrc[(size_t)src * 64 + lane]);
        const float m = fmaxf(bf2f(Ts[tl][lane]) + bv + __int_as_float(it.y) * sfWe, 0.f);
        atomicAdd(&Gs[tl][lane], m);
        if (lane == 0) atomicAdd(&ds[tl], 1);
    }
    __syncthreads();
    for (int i = tid; i < BROWS * 64; i += 256) {
        const int rr = i >> 6;
        if (r0 + rr < N) G[(size_t)(r0 + rr) * 64 + (i & 63)] = ((float*)Gs)[i];
    }
    for (int i = tid; i < BROWS; i += 256)
        if (r0 + i < N) deg[r0 + i] = ds[i];
}

// ---------------------------------------------------------------------------
// Embed kernel (standalone — 16 KB LDS).
// ---------------------------------------------------------------------------
struct EmbedArgs {
    int tC, tV;
    const float* cf; int NC;
    const float* c_shift; const float* c_scale;
    const float* vf; int NV;
    const float* v_shift; const float* v_scale;
    const unsigned short *cW1h, *cW1l, *cW2h, *cW2l, *cWt1h, *cWt1l;
    const unsigned short *vW1h, *vW1l, *vW2h, *vW2l, *vWt1h, *vWt1l, *vWt2h, *vWt2l;
    const float *c_b1, *c_b2, *v_b1, *v_b2, *vc_bl;
    const float *vc_sf, *cv_sf;
    float* Emc; float* Emv;
    unsigned short* A1; unsigned short* B1; unsigned short* B2;
};

__global__ __launch_bounds__(256)
void embed_kernel(EmbedArgs a)
{
    __shared__ __align__(16) float Bb[4][1024];

    int tile = blockIdx.x;
    const float* x; int N; int IN;
    const float *shift, *scale, *b1, *b2, *bt1;
    const unsigned short *W1h, *W1l, *W2h, *W2l, *Wt1h, *Wt1l;
    const unsigned short *Wt2h = nullptr, *Wt2l = nullptr;
    float* Em; unsigned short* T1; unsigned short* T2 = nullptr;
    float sf1, sf2 = 0.f;
    if (tile < a.tC) {
        x = a.cf; N = a.NC; IN = 5; shift = a.c_shift; scale = a.c_scale;
        W1h = a.cW1h; W1l = a.cW1l; b1 = a.c_b1;
        W2h = a.cW2h; W2l = a.cW2l; b2 = a.c_b2;
        Em = a.Emc; Wt1h = a.cWt1h; Wt1l = a.cWt1l; bt1 = a.vc_bl;
        sf1 = a.vc_sf[0]; T1 = a.A1;
    } else {
        tile -= a.tC;
        x = a.vf; N = a.NV; IN = 19; shift = a.v_shift; scale = a.v_scale;
        W1h = a.vW1h; W1l = a.vW1l; b1 = a.v_b1;
        W2h = a.vW2h; W2l = a.vW2l; b2 = a.v_b2;
        Em = a.Emv; Wt1h = a.vWt1h; Wt1l = a.vWt1l; bt1 = nullptr;
        sf1 = a.vc_sf[0]; T1 = a.B1;
        Wt2h = a.vWt2h; Wt2l = a.vWt2l; sf2 = a.cv_sf[0]; T2 = a.B2;
    }

    const int w = threadIdx.x >> 6, lane = threadIdx.x & 63;
    const int l15 = lane & 15, q = lane >> 4;
    const int rbase = tile * 64 + w * 16;

    {
        f32x4 acc[4] = {{0,0,0,0},{0,0,0,0},{0,0,0,0},{0,0,0,0}};
        const int grow = rbase + l15;
        float a8[8];
        #pragma unroll
        for (int j = 0; j < 8; ++j) {
            const int col = q * 8 + j;
            float v = 0.f;
            if (grow < N && col < IN) v = (x[(size_t)grow * IN + col] - shift[col]) * scale[col];
            a8[j] = v;
        }
        short8 ah, al;
        make_hilo(a8, ah, al);
        mfma3(acc, ah, al, W1h, W1l, 1, 0, lane);
        #pragma unroll
        for (int c = 0; c < 4; ++c) {
            const int col = c * 16 + l15;
            const float bb = b1[col];
            #pragma unroll
            for (int r = 0; r < 4; ++r)
                Bb[w][swf(q * 4 + r, col)] = fmaxf(acc[c][r] + bb, 0.f);
        }
    }
    {
        f32x4 acc[4] = {{0,0,0,0},{0,0,0,0},{0,0,0,0},{0,0,0,0}};
        gemm_lds(acc, Bb[w], W2h, W2l, 2, 0, 2, l15, q, lane);
        #pragma unroll
        for (int c = 0; c < 4; ++c) {
            const int col = c * 16 + l15;
            const float bb = b2[col];
            #pragma unroll
            for (int r = 0; r < 4; ++r) {
                const int row = q * 4 + r;
                const int grow = rbase + row;
                const float v = fmaxf(acc[c][r] + bb, 0.f);
                Bb[w][swf(row, col)] = v;
                if (grow < N) Em[(size_t)grow * 64 + col] = v;
            }
        }
    }
    {
        f32x4 acc[4] = {{0,0,0,0},{0,0,0,0},{0,0,0,0},{0,0,0,0}};
        gemm_lds(acc, Bb[w], Wt1h, Wt1l, 2, 0, 2, l15, q, lane);
        #pragma unroll
        for (int c = 0; c < 4; ++c) {
            const int col = c * 16 + l15;
            const float bb = bt1 ? bt1[col] : 0.f;
            #pragma unroll
            for (int r = 0; r < 4; ++r) {
                const int grow = rbase + q * 4 + r;
                if (grow < N) T1[(size_t)grow * 64 + col] = f2bf(sf1 * (acc[c][r] + bb));
            }
        }
    }
    if (T2 != nullptr) {
        f32x4 acc[4] = {{0,0,0,0},{0,0,0,0},{0,0,0,0},{0,0,0,0}};
        gemm_lds(acc, Bb[w], Wt2h, Wt2l, 2, 0, 2, l15, q, lane);
        #pragma unroll
        for (int c = 0; c < 4; ++c) {
            const int col = c * 16 + l15;
            #pragma unroll
            for (int r = 0; r < 4; ++r) {
                const int grow = rbase + q * 4 + r;
                if (grow < N) T2[(size_t)grow * 64 + col] = f2bf(sf2 * acc[c][r]);
            }
        }
    }
}

// ---------------------------------------------------------------------------
// Post-conv (deg[] replaces rs[] for the degree term; otherwise unchanged)
// ---------------------------------------------------------------------------
template<bool IS_POST2>
__global__ __launch_bounds__(256)
void post_mfma(int N, const float* __restrict__ G, const int* __restrict__ deg,
               const float* __restrict__ Em,
               const unsigned short* __restrict__ Wfh, const unsigned short* __restrict__ Wfl,
               const float* __restrict__ bfv, const float* __restrict__ spp,
               const unsigned short* __restrict__ Woah, const unsigned short* __restrict__ Woal,
               const float* __restrict__ boa,
               const unsigned short* __restrict__ Wobh, const unsigned short* __restrict__ Wobl,
               const float* __restrict__ bob,
               const unsigned short* __restrict__ W4h, const unsigned short* __restrict__ W4l,
               const float* __restrict__ b4,
               const float* __restrict__ sf2p, unsigned short* __restrict__ A2,
               const float* __restrict__ oW2, float* __restrict__ out)
{
    __shared__ __align__(16) float BA[4][1024];
    __shared__ __align__(16) float BB[4][1024];

    const int w = threadIdx.x >> 6, lane = threadIdx.x & 63;
    const int l15 = lane & 15, q = lane >> 4;
    const float sp = spp[0];
    const float sf2 = IS_POST2 ? 0.f : sf2p[0];
    const int rbase = blockIdx.x * 64 + w * 16;

    {
        f32x4 acc[4] = {{0,0,0,0},{0,0,0,0},{0,0,0,0},{0,0,0,0}};
        gemm_glb(acc, G, rbase, N, Wfh, Wfl, 2, 0, 2, l15, q, lane);
        float dgr[4];
        #pragma unroll
        for (int r = 0; r < 4; ++r) {
            const int grow = rbase + q * 4 + r;
            dgr[r] = (grow < N) ? (float)deg[grow] : 0.f;
        }
        #pragma unroll
        for (int c = 0; c < 4; ++c) {
            const int col = c * 16 + l15;
            const float bb = bfv[col];
            #pragma unroll
            for (int r = 0; r < 4; ++r)
                BA[w][swf(q * 4 + r, col)] = (acc[c][r] + dgr[r] * bb) * sp;
        }
    }
    {
        f32x4 acc[4] = {{0,0,0,0},{0,0,0,0},{0,0,0,0},{0,0,0,0}};
        gemm_lds(acc, BA[w], Woah, Woal, 4, 0, 2, l15, q, lane);
        gemm_glb(acc, Em, rbase, N, Woah, Woal, 4, 2, 2, l15, q, lane);
        #pragma unroll
        for (int c = 0; c < 4; ++c) {
            const int col = c * 16 + l15;
            const float bb = boa[col];
            #pragma unroll
            for (int r = 0; r < 4; ++r)
                BB[w][swf(q * 4 + r, col)] = fmaxf(acc[c][r] + bb, 0.f);
        }
    }
    {
        f32x4 acc[4] = {{0,0,0,0},{0,0,0,0},{0,0,0,0},{0,0,0,0}};
        gemm_lds(acc, BB[w], Wobh, Wobl, 2, 0, 2, l15, q, lane);
        #pragma unroll
        for (int c = 0; c < 4; ++c) {
            const int col = c * 16 + l15;
            const float bb = bob[col];
            #pragma unroll
            for (int r = 0; r < 4; ++r)
                BA[w][swf(q * 4 + r, col)] = fmaxf(acc[c][r] + bb, 0.f);
        }
    }
    {
        f32x4 acc[4] = {{0,0,0,0},{0,0,0,0},{0,0,0,0},{0,0,0,0}};
        gemm_lds(acc, BA[w], W4h, W4l, 2, 0, 2, l15, q, lane);
        if (!IS_POST2) {
            #pragma unroll
            for (int c = 0; c < 4; ++c) {
                const int col = c * 16 + l15;
                const float bb = b4[col];
                #pragma unroll
                for (int r = 0; r < 4; ++r) {
                    const int grow = rbase + q * 4 + r;
                    if (grow < N) A2[(size_t)grow * 64 + col] = f2bf(sf2 * (acc[c][r] + bb));
                }
            }
        } else {
            float w2c[4], bb4[4];
            #pragma unroll
            for (int c = 0; c < 4; ++c) {
                const int col = c * 16 + l15;
                w2c[c] = oW2[col];
                bb4[c] = b4[col];
            }
            #pragma unroll
            for (int r = 0; r < 4; ++r) {
                float s = 0.f;
                #pragma unroll
                for (int c = 0; c < 4; ++c)
                    s += fmaxf(acc[c][r] + bb4[c], 0.f) * w2c[c];
                s += __shfl_xor(s, 1);
                s += __shfl_xor(s, 2);
                s += __shfl_xor(s, 4);
                s += __shfl_xor(s, 8);
                const int grow = rbase + q * 4 + r;
                if (l15 == 0 && grow < N) out[grow] = s;
            }
        }
    }
}

// ---------------------------------------------------------------------------
extern "C" void kernel_launch(void* const* d_in, const int* in_sizes, int n_in,
                              void* d_out, int out_size, void* d_ws, size_t ws_size,
                              hipStream_t stream)
{
    const float* cf      = (const float*)d_in[0];
    const float* ef      = (const float*)d_in[1];
    const float* vf      = (const float*)d_in[2];
    const float* c_shift = (const float*)d_in[3];
    const float* c_scale = (const float*)d_in[4];
    const float* v_shift = (const float*)d_in[5];
    const float* v_scale = (const float*)d_in[6];
    const float* e_shift = (const float*)d_in[7];
    const float* e_scale = (const float*)d_in[8];
    const float* c_W1 = (const float*)d_in[9];
    const float* c_b1 = (const float*)d_in[10];
    const float* c_W2 = (const float*)d_in[11];
    const float* c_b2 = (const float*)d_in[12];
    const float* v_W1 = (const float*)d_in[13];
    const float* v_b1 = (const float*)d_in[14];
    const float* v_W2 = (const float*)d_in[15];
    const float* v_b2 = (const float*)d_in[16];
    const float* vc_Wl  = (const float*)d_in[17];
    const float* vc_bl  = (const float*)d_in[18];
    const float* vc_We  = (const float*)d_in[19];
    const float* vc_Wr  = (const float*)d_in[20];
    const float* vc_sf  = (const float*)d_in[21];
    const float* vc_Wf  = (const float*)d_in[22];
    const float* vc_bf  = (const float*)d_in[23];
    const float* vc_sp  = (const float*)d_in[24];
    const float* vc_Woa = (const float*)d_in[25];
    const float* vc_boa = (const float*)d_in[26];
    const float* vc_Wob = (const float*)d_in[27];
    const float* vc_bob = (const float*)d_in[28];
    const float* cv_Wl  = (const float*)d_in[29];
    const float* cv_bl  = (const float*)d_in[30];
    const float* cv_We  = (const float*)d_in[31];
    const float* cv_Wr  = (const float*)d_in[32];
    const float* cv_sf  = (const float*)d_in[33];
    const float* cv_Wf  = (const float*)d_in[34];
    const float* cv_bf  = (const float*)d_in[35];
    const float* cv_sp  = (const float*)d_in[36];
    const float* cv_Woa = (const float*)d_in[37];
    const float* cv_boa = (const float*)d_in[38];
    const float* cv_Wob = (const float*)d_in[39];
    const float* cv_bob = (const float*)d_in[40];
    const float* out_W1 = (const float*)d_in[41];
    const float* out_b1 = (const float*)d_in[42];
    const float* out_W2 = (const float*)d_in[43];
    const int*   eidx   = (const int*)d_in[44];

    const int NC = in_sizes[0] / 5;
    const int NV = in_sizes[2] / 19;
    const int E  = in_sizes[1];

    const int nb1 = (NC + BROWS - 1) / BROWS;
    const int nb2 = (NV + BROWS - 1) / BROWS;
    const int nbm = nb1 > nb2 ? nb1 : nb2;
    const int chunk_len = (((E + NCHUNK - 1) / NCHUNK) + 3) & ~3;

    // ---- workspace layout (256B aligned slots, no aliasing needed) ----
    char* ws = (char*)d_ws;
    size_t off = 0;
    auto alloc = [&](size_t bytes) -> size_t {
        size_t o = off;
        off = (off + bytes + 255) & ~(size_t)255;
        return o;
    };
    size_t o_items1 = alloc((size_t)E * 8);
    size_t o_items2 = alloc((size_t)E * 8);
    size_t o_cnt1   = alloc((size_t)NCHUNK * nb1 * 4);
    size_t o_cnt2   = alloc((size_t)NCHUNK * nb2 * 4);
    size_t o_tot1   = alloc((size_t)nb1 * 4);
    size_t o_tot2   = alloc((size_t)nb2 * 4);
    size_t o_bs1    = alloc((size_t)(nb1 + 1) * 4);
    size_t o_bs2    = alloc((size_t)(nb2 + 1) * 4);
    size_t o_deg1   = alloc((size_t)NC * 4);
    size_t o_deg2   = alloc((size_t)NV * 4);
    size_t o_G1     = alloc((size_t)NC * 64 * 4);
    size_t o_G2     = alloc((size_t)NV * 64 * 4);
    size_t o_Emc    = alloc((size_t)NC * 64 * 4);
    size_t o_Emv    = alloc((size_t)NV * 64 * 4);
    size_t o_A1     = alloc((size_t)NC * 64 * 2);
    size_t o_B1     = alloc((size_t)NV * 64 * 2);
    size_t o_B2     = alloc((size_t)NV * 64 * 2);

    static const int nkt_arr[NMAT] = {1,2,2,1,2,2,2,2,4,2,2,2,4,2,2};
    static const int KR_arr[NMAT]  = {5,64,64,19,64,64,64,64,128,64,64,64,128,64,64};
    const float* src_arr[NMAT] = {c_W1, c_W2, vc_Wl, v_W1, v_W2, vc_Wr, cv_Wr,
                                  vc_Wf, vc_Woa, vc_Wob, cv_Wl,
                                  cv_Wf, cv_Woa, cv_Wob, out_W1};
    size_t o_wh[NMAT], o_wl[NMAT];
    for (int m = 0; m < NMAT; ++m) {
        o_wh[m] = alloc((size_t)nkt_arr[m] * 4 * 64 * 8 * 2);
        o_wl[m] = alloc((size_t)nkt_arr[m] * 4 * 64 * 8 * 2);
    }
    (void)ws_size; (void)n_in; (void)out_size;

    int2* items1 = (int2*)(ws + o_items1);
    int2* items2 = (int2*)(ws + o_items2);
    int*  cnt1 = (int*)(ws + o_cnt1);
    int*  cnt2 = (int*)(ws + o_cnt2);
    int*  tot1 = (int*)(ws + o_tot1);
    int*  tot2 = (int*)(ws + o_tot2);
    int*  bs1  = (int*)(ws + o_bs1);
    int*  bs2  = (int*)(ws + o_bs2);
    int*  deg1 = (int*)(ws + o_deg1);
    int*  deg2 = (int*)(ws + o_deg2);
    float* G1  = (float*)(ws + o_G1);
    float* G2  = (float*)(ws + o_G2);
    float* Emc = (float*)(ws + o_Emc);
    float* Emv = (float*)(ws + o_Emv);
    unsigned short* A1 = (unsigned short*)(ws + o_A1);
    unsigned short* B1 = (unsigned short*)(ws + o_B1);
    unsigned short* A2 = (unsigned short*)(ws + o_A1);  // alias (A1 dead after agg1)
    unsigned short* B2 = (unsigned short*)(ws + o_B2);

    PrepArgs pa;
    for (int m = 0; m < NMAT; ++m) {
        pa.src[m] = src_arr[m];
        pa.hi[m] = (unsigned short*)(ws + o_wh[m]);
        pa.lo[m] = (unsigned short*)(ws + o_wl[m]);
        pa.nkt[m] = nkt_arr[m];
        pa.KR[m] = KR_arr[m];
    }
    auto WH = [&](int m) { return (const unsigned short*)(ws + o_wh[m]); };
    auto WL = [&](int m) { return (const unsigned short*)(ws + o_wl[m]); };

    // --- weight prep ---
    prep_kernel<<<dim3(4, NMAT), 256, 0, stream>>>(pa);

    // --- bucket multisplit (count -> totals -> scan -> offsets -> scatter) ---
    count_bkt<<<dim3(NCHUNK, 2), 256, 0, stream>>>(
        eidx, E, chunk_len, nb1, nb2, cnt1, cnt2);
    total_bkt<<<dim3((nbm + 255) / 256, 2), 256, 0, stream>>>(
        cnt1, nb1, tot1, cnt2, nb2, tot2);
    bscan_bkt<<<2, 256, 0, stream>>>(tot1, nb1, bs1, tot2, nb2, bs2);
    off_bkt<<<dim3((nbm + 255) / 256, 2), 256, 0, stream>>>(
        cnt1, nb1, bs1, cnt2, nb2, bs2);
    scatter_bkt<<<dim3(NCHUNK, 2), 256, 0, stream>>>(
        eidx, E, chunk_len, ef, e_shift, e_scale,
        nb1, nb2, cnt1, cnt2, items1, items2);

    // --- embeddings ---
    const int tC = (NC + 63) >> 6, tV = (NV + 63) >> 6;
    EmbedArgs ea;
    ea.tC = tC; ea.tV = tV;
    ea.cf = cf; ea.NC = NC; ea.c_shift = c_shift; ea.c_scale = c_scale;
    ea.vf = vf; ea.NV = NV; ea.v_shift = v_shift; ea.v_scale = v_scale;
    ea.cW1h = WH(0); ea.cW1l = WL(0); ea.cW2h = WH(1); ea.cW2l = WL(1);
    ea.cWt1h = WH(2); ea.cWt1l = WL(2);
    ea.vW1h = WH(3); ea.vW1l = WL(3); ea.vW2h = WH(4); ea.vW2l = WL(4);
    ea.vWt1h = WH(5); ea.vWt1l = WL(5); ea.vWt2h = WH(6); ea.vWt2l = WL(6);
    ea.c_b1 = c_b1; ea.c_b2 = c_b2; ea.v_b1 = v_b1; ea.v_b2 = v_b2;
    ea.vc_bl = vc_bl; ea.vc_sf = vc_sf; ea.cv_sf = cv_sf;
    ea.Emc = Emc; ea.Emv = Emv; ea.A1 = A1; ea.B1 = B1; ea.B2 = B2;
    embed_kernel<<<tC + tV, 256, 0, stream>>>(ea);

    // --- conv1: target = constraints (dir1), Ttgt=A1, Tsrc=B1 ---
    agg_bkt<<<nb1, 256, 0, stream>>>(
        NC, bs1, items1, A1, B1, vc_We, vc_sf, G1, deg1);
    post_mfma<false><<<tC, 256, 0, stream>>>(
        NC, G1, deg1, Emc,
        WH(7), WL(7), vc_bf, vc_sp,
        WH(8), WL(8), vc_boa,
        WH(9), WL(9), vc_bob,
        WH(10), WL(10), cv_bl,
        cv_sf, A2, nullptr, nullptr);

    // --- conv2: target = variables (dir2), Ttgt=B2, Tsrc=A2 ---
    agg_bkt<<<nb2, 256, 0, stream>>>(
        NV, bs2, items2, B2, A2, cv_We, cv_sf, G2, deg2);
    post_mfma<true><<<tV, 256, 0, stream>>>(
        NV, G2, deg2, Emv,
        WH(11), WL(11), cv_bf, cv_sp,
        WH(12), WL(12), cv_boa,
        WH(13), WL(13), cv_bob,
        WH(14), WL(14), out_b1,
        nullptr, nullptr, out_W2, (float*)d_out);
}

// Round 7
// 749.693 us; speedup vs baseline: 2.6882x; 2.6882x over previous
//
#include <hip/hip_runtime.h>
#include <hip/hip_bf16.h>

#define DEV __device__ __forceinline__

typedef __attribute__((ext_vector_type(8))) short short8;
typedef __attribute__((ext_vector_type(4))) float f32x4;

DEV unsigned short f2bf(float f) {
    __hip_bfloat16 h = __float2bfloat16(f);
    unsigned short u;
    __builtin_memcpy(&u, &h, 2);
    return u;
}
DEV float bf2f(unsigned short u) { return __uint_as_float((unsigned int)u << 16); }

DEV f32x4 mfma_bf16(short8 a, short8 b, f32x4 c) {
    return __builtin_amdgcn_mfma_f32_16x16x32_bf16(a, b, c, 0, 0, 0);
}

// fp32 -> (hi, lo) bf16 pair; hi+lo represents v to ~2^-17 rel.
DEV void make_hilo(const float* a8, short8& hi, short8& lo) {
    #pragma unroll
    for (int j = 0; j < 8; ++j) {
        const float v = a8[j];
        const unsigned short h = f2bf(v);
        hi[j] = (short)h;
        lo[j] = (short)f2bf(v - bf2f(h));
    }
}

// 3-term split-precision MFMA accumulate against 4 column-frags.
DEV void mfma3(f32x4 acc[4], short8 ah, short8 al,
               const unsigned short* __restrict__ Bh,
               const unsigned short* __restrict__ Bl,
               int nkt, int tidx, int lane) {
    #pragma unroll
    for (int c = 0; c < 4; ++c) {
        const size_t o = ((size_t)(c * nkt + tidx) * 64 + lane) * 8;
        const short8 bh = *(const short8*)(Bh + o);
        const short8 bl = *(const short8*)(Bl + o);
        acc[c] = mfma_bf16(ah, bh, acc[c]);
        acc[c] = mfma_bf16(al, bh, acc[c]);
        acc[c] = mfma_bf16(ah, bl, acc[c]);
    }
}

// XOR-chunk-swizzled fp32 activation buffer (16 rows x 64)
DEV int swf(int row, int col) {
    return row * 64 + ((((col >> 3) ^ row) & 7) << 3) + (col & 7);
}

DEV void gemm_lds(f32x4 acc[4], const float* Xl,
                  const unsigned short* Bh, const unsigned short* Bl,
                  int nkt, int t0, int ntk, int l15, int q, int lane) {
    for (int t = 0; t < ntk; ++t) {
        const int ch = (t * 4 + q) ^ (l15 & 7);
        const float* a8 = Xl + l15 * 64 + ch * 8;
        short8 ah, al;
        make_hilo(a8, ah, al);
        mfma3(acc, ah, al, Bh, Bl, nkt, t0 + t, lane);
    }
}

DEV void gemm_glb(f32x4 acc[4], const float* __restrict__ Xg, int rbase, int N,
                  const unsigned short* Bh, const unsigned short* Bl,
                  int nkt, int t0, int ntk, int l15, int q, int lane) {
    const int grow = rbase + l15;
    const bool ok = grow < N;
    for (int t = 0; t < ntk; ++t) {
        float a8[8];
        if (ok) {
            const float4 v0 = *(const float4*)(Xg + (size_t)grow * 64 + t * 32 + q * 8);
            const float4 v1 = *(const float4*)(Xg + (size_t)grow * 64 + t * 32 + q * 8 + 4);
            a8[0] = v0.x; a8[1] = v0.y; a8[2] = v0.z; a8[3] = v0.w;
            a8[4] = v1.x; a8[5] = v1.y; a8[6] = v1.z; a8[7] = v1.w;
        } else {
            #pragma unroll
            for (int j = 0; j < 8; ++j) a8[j] = 0.f;
        }
        short8 ah, al;
        make_hilo(a8, ah, al);
        mfma3(acc, ah, al, Bh, Bl, nkt, t0 + t, lane);
    }
}

// ---------------------------------------------------------------------------
// Weight prep (unchanged)
// ---------------------------------------------------------------------------
#define NMAT 15
struct PrepArgs {
    const float* src[NMAT];
    unsigned short* hi[NMAT];
    unsigned short* lo[NMAT];
    int nkt[NMAT];
    int KR[NMAT];
};

__global__ __launch_bounds__(256)
void prep_kernel(PrepArgs pa)
{
    const int m = blockIdx.y;
    const int nkt = pa.nkt[m];
    const int nthr = nkt * 4 * 64;
    const int p = blockIdx.x * 256 + threadIdx.x;
    if (p >= nthr) return;
    const int f = p >> 6, l = p & 63;
    const int c = f / nkt, t = f % nkt;
    const int kbase = t * 32 + ((l >> 4) << 3);
    const int n = c * 16 + (l & 15);
    const float* W = pa.src[m];
    const int KR = pa.KR[m];
    unsigned short* ph = pa.hi[m] + (size_t)p * 8;
    unsigned short* pl = pa.lo[m] + (size_t)p * 8;
    #pragma unroll
    for (int j = 0; j < 8; ++j) {
        const int k = kbase + j;
        const float v = (k < KR) ? W[k * 64 + n] : 0.f;
        const unsigned short h = f2bf(v);
        ph[j] = h;
        pl[j] = f2bf(v - bf2f(h));
    }
}

// ---------------------------------------------------------------------------
// Fused hist(+rank) / embed kernel — the R0-measured configuration (173us,
// best stage-1 across all 6 alternatives tried; hist's global-atomic latency
// hides under embed compute on shared CUs).
// ---------------------------------------------------------------------------
struct FusedArgs {
    const int* ei; int E; int nH;
    int* h1; int* h2; unsigned int* rank;
    int tC, tV;
    const float* cf; int NC;
    const float* c_shift; const float* c_scale;
    const float* vf; int NV;
    const float* v_shift; const float* v_scale;
    const unsigned short *cW1h, *cW1l, *cW2h, *cW2l, *cWt1h, *cWt1l;
    const unsigned short *vW1h, *vW1l, *vW2h, *vW2l, *vWt1h, *vWt1l, *vWt2h, *vWt2l;
    const float *c_b1, *c_b2, *v_b1, *v_b2, *vc_bl;
    const float *vc_sf, *cv_sf;
    float* Emc; float* Emv;
    unsigned short* A1; unsigned short* B1; unsigned short* B2;
};

__global__ __launch_bounds__(256)
void fused_he_kernel(FusedArgs a)
{
    __shared__ __align__(16) float Bb[4][1024];

    const int half = blockIdx.x & 1;
    const int idx  = blockIdx.x >> 1;

    if (half == 0) {
        const int stride = a.nH * 256;
        for (int e = idx * 256 + (int)threadIdx.x; e < a.E; e += stride) {
            const int r1 = atomicAdd(a.h1 + a.ei[e], 1);
            const int r2 = atomicAdd(a.h2 + a.ei[a.E + e], 1);
            a.rank[e] = (unsigned int)r1 | ((unsigned int)r2 << 16);
        }
        return;
    }

    int tile = idx;
    const float* x; int N; int IN;
    const float *shift, *scale, *b1, *b2, *bt1;
    const unsigned short *W1h, *W1l, *W2h, *W2l, *Wt1h, *Wt1l;
    const unsigned short *Wt2h = nullptr, *Wt2l = nullptr;
    float* Em; unsigned short* T1; unsigned short* T2 = nullptr;
    float sf1, sf2 = 0.f;
    if (tile < a.tC) {
        x = a.cf; N = a.NC; IN = 5; shift = a.c_shift; scale = a.c_scale;
        W1h = a.cW1h; W1l = a.cW1l; b1 = a.c_b1;
        W2h = a.cW2h; W2l = a.cW2l; b2 = a.c_b2;
        Em = a.Emc; Wt1h = a.cWt1h; Wt1l = a.cWt1l; bt1 = a.vc_bl;
        sf1 = a.vc_sf[0]; T1 = a.A1;
    } else {
        tile -= a.tC;
        x = a.vf; N = a.NV; IN = 19; shift = a.v_shift; scale = a.v_scale;
        W1h = a.vW1h; W1l = a.vW1l; b1 = a.v_b1;
        W2h = a.vW2h; W2l = a.vW2l; b2 = a.v_b2;
        Em = a.Emv; Wt1h = a.vWt1h; Wt1l = a.vWt1l; bt1 = nullptr;
        sf1 = a.vc_sf[0]; T1 = a.B1;
        Wt2h = a.vWt2h; Wt2l = a.vWt2l; sf2 = a.cv_sf[0]; T2 = a.B2;
    }

    const int w = threadIdx.x >> 6, lane = threadIdx.x & 63;
    const int l15 = lane & 15, q = lane >> 4;
    const int rbase = tile * 64 + w * 16;

    {
        f32x4 acc[4] = {{0,0,0,0},{0,0,0,0},{0,0,0,0},{0,0,0,0}};
        const int grow = rbase + l15;
        float a8[8];
        #pragma unroll
        for (int j = 0; j < 8; ++j) {
            const int col = q * 8 + j;
            float v = 0.f;
            if (grow < N && col < IN) v = (x[(size_t)grow * IN + col] - shift[col]) * scale[col];
            a8[j] = v;
        }
        short8 ah, al;
        make_hilo(a8, ah, al);
        mfma3(acc, ah, al, W1h, W1l, 1, 0, lane);
        #pragma unroll
        for (int c = 0; c < 4; ++c) {
            const int col = c * 16 + l15;
            const float bb = b1[col];
            #pragma unroll
            for (int r = 0; r < 4; ++r)
                Bb[w][swf(q * 4 + r, col)] = fmaxf(acc[c][r] + bb, 0.f);
        }
    }
    {
        f32x4 acc[4] = {{0,0,0,0},{0,0,0,0},{0,0,0,0},{0,0,0,0}};
        gemm_lds(acc, Bb[w], W2h, W2l, 2, 0, 2, l15, q, lane);
        #pragma unroll
        for (int c = 0; c < 4; ++c) {
            const int col = c * 16 + l15;
            const float bb = b2[col];
            #pragma unroll
            for (int r = 0; r < 4; ++r) {
                const int row = q * 4 + r;
                const int grow = rbase + row;
                const float v = fmaxf(acc[c][r] + bb, 0.f);
                Bb[w][swf(row, col)] = v;
                if (grow < N) Em[(size_t)grow * 64 + col] = v;
            }
        }
    }
    {
        f32x4 acc[4] = {{0,0,0,0},{0,0,0,0},{0,0,0,0},{0,0,0,0}};
        gemm_lds(acc, Bb[w], Wt1h, Wt1l, 2, 0, 2, l15, q, lane);
        #pragma unroll
        for (int c = 0; c < 4; ++c) {
            const int col = c * 16 + l15;
            const float bb = bt1 ? bt1[col] : 0.f;
            #pragma unroll
            for (int r = 0; r < 4; ++r) {
                const int grow = rbase + q * 4 + r;
                if (grow < N) T1[(size_t)grow * 64 + col] = f2bf(sf1 * (acc[c][r] + bb));
            }
        }
    }
    if (T2 != nullptr) {
        f32x4 acc[4] = {{0,0,0,0},{0,0,0,0},{0,0,0,0},{0,0,0,0}};
        gemm_lds(acc, Bb[w], Wt2h, Wt2l, 2, 0, 2, l15, q, lane);
        #pragma unroll
        for (int c = 0; c < 4; ++c) {
            const int col = c * 16 + l15;
            #pragma unroll
            for (int r = 0; r < 4; ++r) {
                const int grow = rbase + q * 4 + r;
                if (grow < N) T2[(size_t)grow * 64 + col] = f2bf(sf2 * acc[c][r]);
            }
        }
    }
}

// ---------------------------------------------------------------------------
// Post-conv (R0 form: degree from rs)
// ---------------------------------------------------------------------------
template<bool IS_POST2>
__global__ __launch_bounds__(256)
void post_mfma(int N, const float* __restrict__ G, const int* __restrict__ rs,
               const float* __restrict__ Em,
               const unsigned short* __restrict__ Wfh, const unsigned short* __restrict__ Wfl,
               const float* __restrict__ bfv, const float* __restrict__ spp,
               const unsigned short* __restrict__ Woah, const unsigned short* __restrict__ Woal,
               const float* __restrict__ boa,
               const unsigned short* __restrict__ Wobh, const unsigned short* __restrict__ Wobl,
               const float* __restrict__ bob,
               const unsigned short* __restrict__ W4h, const unsigned short* __restrict__ W4l,
               const float* __restrict__ b4,
               const float* __restrict__ sf2p, unsigned short* __restrict__ A2,
               const float* __restrict__ oW2, float* __restrict__ out)
{
    __shared__ __align__(16) float BA[4][1024];
    __shared__ __align__(16) float BB[4][1024];

    const int w = threadIdx.x >> 6, lane = threadIdx.x & 63;
    const int l15 = lane & 15, q = lane >> 4;
    const float sp = spp[0];
    const float sf2 = IS_POST2 ? 0.f : sf2p[0];
    const int rbase = blockIdx.x * 64 + w * 16;

    {
        f32x4 acc[4] = {{0,0,0,0},{0,0,0,0},{0,0,0,0},{0,0,0,0}};
        gemm_glb(acc, G, rbase, N, Wfh, Wfl, 2, 0, 2, l15, q, lane);
        float dgr[4];
        #pragma unroll
        for (int r = 0; r < 4; ++r) {
            const int grow = rbase + q * 4 + r;
            dgr[r] = (grow < N) ? (float)(rs[grow + 1] - rs[grow]) : 0.f;
        }
        #pragma unroll
        for (int c = 0; c < 4; ++c) {
            const int col = c * 16 + l15;
            const float bb = bfv[col];
            #pragma unroll
            for (int r = 0; r < 4; ++r)
                BA[w][swf(q * 4 + r, col)] = (acc[c][r] + dgr[r] * bb) * sp;
        }
    }
    {
        f32x4 acc[4] = {{0,0,0,0},{0,0,0,0},{0,0,0,0},{0,0,0,0}};
        gemm_lds(acc, BA[w], Woah, Woal, 4, 0, 2, l15, q, lane);
        gemm_glb(acc, Em, rbase, N, Woah, Woal, 4, 2, 2, l15, q, lane);
        #pragma unroll
        for (int c = 0; c < 4; ++c) {
            const int col = c * 16 + l15;
            const float bb = boa[col];
            #pragma unroll
            for (int r = 0; r < 4; ++r)
                BB[w][swf(q * 4 + r, col)] = fmaxf(acc[c][r] + bb, 0.f);
        }
    }
    {
        f32x4 acc[4] = {{0,0,0,0},{0,0,0,0},{0,0,0,0},{0,0,0,0}};
        gemm_lds(acc, BB[w], Wobh, Wobl, 2, 0, 2, l15, q, lane);
        #pragma unroll
        for (int c = 0; c < 4; ++c) {
            const int col = c * 16 + l15;
            const float bb = bob[col];
            #pragma unroll
            for (int r = 0; r < 4; ++r)
                BA[w][swf(q * 4 + r, col)] = fmaxf(acc[c][r] + bb, 0.f);
        }
    }
    {
        f32x4 acc[4] = {{0,0,0,0},{0,0,0,0},{0,0,0,0},{0,0,0,0}};
        gemm_lds(acc, BA[w], W4h, W4l, 2, 0, 2, l15, q, lane);
        if (!IS_POST2) {
            #pragma unroll
            for (int c = 0; c < 4; ++c) {
                const int col = c * 16 + l15;
                const float bb = b4[col];
                #pragma unroll
                for (int r = 0; r < 4; ++r) {
                    const int grow = rbase + q * 4 + r;
                    if (grow < N) A2[(size_t)grow * 64 + col] = f2bf(sf2 * (acc[c][r] + bb));
                }
            }
        } else {
            float w2c[4], bb4[4];
            #pragma unroll
            for (int c = 0; c < 4; ++c) {
                const int col = c * 16 + l15;
                w2c[c] = oW2[col];
                bb4[c] = b4[col];
            }
            #pragma unroll
            for (int r = 0; r < 4; ++r) {
                float s = 0.f;
                #pragma unroll
                for (int c = 0; c < 4; ++c)
                    s += fmaxf(acc[c][r] + bb4[c], 0.f) * w2c[c];
                s += __shfl_xor(s, 1);
                s += __shfl_xor(s, 2);
                s += __shfl_xor(s, 4);
                s += __shfl_xor(s, 8);
                const int grow = rbase + q * 4 + r;
                if (l15 == 0 && grow < N) out[grow] = s;
            }
        }
    }
}

// ---------------------------------------------------------------------------
// Multiblock scans (R0)
// ---------------------------------------------------------------------------
__global__ __launch_bounds__(256)
void scanA2_kernel(const int* __restrict__ h1, int n1, int* __restrict__ cs1,
                   const int* __restrict__ h2, int n2, int* __restrict__ cs2)
{
    __shared__ int wsum[4];
    const int which = blockIdx.y;
    const int* h = which ? h2 : h1;
    const int n = which ? n2 : n1;
    int* csum = which ? cs2 : cs1;
    if (blockIdx.x * 4096 >= n) return;

    const int t = threadIdx.x, lane = t & 63, wid = t >> 6;
    const int base = blockIdx.x * 4096 + t * 16;
    int s = 0;
    #pragma unroll
    for (int j = 0; j < 16; ++j) {
        const int idx = base + j;
        if (idx < n) s += h[idx];
    }
    #pragma unroll
    for (int d = 1; d < 64; d <<= 1) s += __shfl_xor(s, d);
    if (lane == 0) wsum[wid] = s;
    __syncthreads();
    if (t == 0) csum[blockIdx.x] = wsum[0] + wsum[1] + wsum[2] + wsum[3];
}

__global__ __launch_bounds__(256)
void scanB2_kernel(int* __restrict__ cs1, int nch1, int* __restrict__ rs1, int n1,
                   int* __restrict__ cs2, int nch2, int* __restrict__ rs2, int n2)
{
    __shared__ int wsum[4];
    const int which = blockIdx.x;
    int* csum = which ? cs2 : cs1;
    const int nchunks = which ? nch2 : nch1;
    int* rs = which ? rs2 : rs1;
    const int n = which ? n2 : n1;

    const int t = threadIdx.x, lane = t & 63, wid = t >> 6;
    const int v = (t < nchunks) ? csum[t] : 0;
    int x = v;
    #pragma unroll
    for (int d = 1; d < 64; d <<= 1) { int y = __shfl_up(x, d); if (lane >= d) x += y; }
    if (lane == 63) wsum[wid] = x;
    __syncthreads();
    int woff = 0;
    for (int i = 0; i < wid; ++i) woff += wsum[i];
    if (t < nchunks) csum[t] = woff + x - v;
    if (t == 0) rs[n] = wsum[0] + wsum[1] + wsum[2] + wsum[3];
}

__global__ __launch_bounds__(256)
void scanC2_kernel(const int* __restrict__ h1, int n1, const int* __restrict__ cs1,
                   int* __restrict__ rs1,
                   const int* __restrict__ h2, int n2, const int* __restrict__ cs2,
                   int* __restrict__ rs2)
{
    __shared__ int wsum[4];
    const int which = blockIdx.y;
    const int* h = which ? h2 : h1;
    const int n = which ? n2 : n1;
    const int* csum = which ? cs2 : cs1;
    int* rs = which ? rs2 : rs1;
    if (blockIdx.x * 4096 >= n) return;

    const int t = threadIdx.x, lane = t & 63, wid = t >> 6;
    const int base = blockIdx.x * 4096 + t * 16;
    int loc[16];
    int s = 0;
    #pragma unroll
    for (int j = 0; j < 16; ++j) {
        loc[j] = s;
        const int idx = base + j;
        if (idx < n) s += h[idx];
    }
    int x = s;
    #pragma unroll
    for (int d = 1; d < 64; d <<= 1) { int y = __shfl_up(x, d); if (lane >= d) x += y; }
    if (lane == 63) wsum[wid] = x;
    __syncthreads();
    int woff = 0;
    for (int i = 0; i < wid; ++i) woff += wsum[i];
    const int toff = csum[blockIdx.x] + woff + x - s;
    #pragma unroll
    for (int j = 0; j < 16; ++j) {
        const int idx = base + j;
        if (idx < n) rs[idx] = toff + loc[j];
    }
}

// ---------------------------------------------------------------------------
// Atomic-free single-pass scatter — R21: stores a 4-byte edge-id per slot
// (was int2 pair). Halves scattered-store bytes -> ~halves partial-line
// write amplification and write-allocate fills; agg re-derives (other
// endpoint, edge value) from L3-resident eidx/ef.
// ---------------------------------------------------------------------------
__global__ __launch_bounds__(256)
void scatter_kernel(const int* __restrict__ ei, int E,
                    const unsigned int* __restrict__ rank,
                    const int* __restrict__ rs1, const int* __restrict__ rs2,
                    unsigned int* __restrict__ items1,
                    unsigned int* __restrict__ items2)
{
    const int e = blockIdx.x * 256 + threadIdx.x;
    if (e >= E) return;
    const int i0 = ei[e];
    const int i1 = ei[E + e];
    const unsigned int rk = rank[e];
    const int pos1 = rs1[i0] + (int)(rk & 0xffffu);
    const int pos2 = rs2[i1] + (int)(rk >> 16);
    items1[pos1] = (unsigned int)e;
    items2[pos2] = (unsigned int)e;
}

// ---------------------------------------------------------------------------
// Gather-aggregate, 8-way unrolled (one row per wave; register accumulation).
// 4B items: id -> oth[id] (other endpoint), ef[id] (edge feature).
// ---------------------------------------------------------------------------
DEV void agg_body(int row, int j, const int* __restrict__ rs,
                  const unsigned int* __restrict__ items,
                  const int* __restrict__ oth, const float* __restrict__ ef,
                  float esh, float esc,
                  const unsigned short* __restrict__ Ttgt,
                  const unsigned short* __restrict__ Tsrc,
                  const float* __restrict__ We, const float* __restrict__ sfp,
                  float* __restrict__ G)
{
    const float base = bf2f(Ttgt[(size_t)row * 64 + j]);
    const float sfWe = sfp[0] * We[j];
    const int s = rs[row];
    const int e = rs[row + 1];
    float acc = 0.f;
    int p = s;
    for (; p + 7 < e; p += 8) {
        unsigned int id[8];
        #pragma unroll
        for (int u = 0; u < 8; ++u) id[u] = items[p + u];
        int o[8];
        float en[8];
        #pragma unroll
        for (int u = 0; u < 8; ++u) o[u] = oth[id[u]];
        #pragma unroll
        for (int u = 0; u < 8; ++u) en[u] = (ef[id[u]] - esh) * esc;
        float b[8];
        #pragma unroll
        for (int u = 0; u < 8; ++u) b[u] = bf2f(Tsrc[(size_t)o[u] * 64 + j]);
        #pragma unroll
        for (int u = 0; u < 8; ++u)
            acc += fmaxf(base + b[u] + en[u] * sfWe, 0.f);
    }
    for (; p < e; ++p) {
        const unsigned int id = items[p];
        const int o = oth[id];
        const float en = (ef[id] - esh) * esc;
        const float bs = bf2f(Tsrc[(size_t)o * 64 + j]);
        acc += fmaxf(base + bs + en * sfWe, 0.f);
    }
    G[(size_t)row * 64 + j] = acc;
}

__global__ __launch_bounds__(256)
void agg_kernel(int nrows, const int* __restrict__ rs,
                const unsigned int* __restrict__ items,
                const int* __restrict__ oth, const float* __restrict__ ef,
                const float* __restrict__ eshp, const float* __restrict__ escp,
                const unsigned short* __restrict__ Ttgt,
                const unsigned short* __restrict__ Tsrc,
                const float* __restrict__ We, const float* __restrict__ sfp,
                float* __restrict__ G)
{
    const int row = blockIdx.x * 4 + (int)(threadIdx.x >> 6);
    if (row >= nrows) return;
    agg_body(row, (int)(threadIdx.x & 63), rs, items, oth, ef,
             eshp[0], escp[0], Ttgt, Tsrc, We, sfp, G);
}

// ---------------------------------------------------------------------------
extern "C" void kernel_launch(void* const* d_in, const int* in_sizes, int n_in,
                              void* d_out, int out_size, void* d_ws, size_t ws_size,
                              hipStream_t stream)
{
    const float* cf      = (const float*)d_in[0];
    const float* ef      = (const float*)d_in[1];
    const float* vf      = (const float*)d_in[2];
    const float* c_shift = (const float*)d_in[3];
    const float* c_scale = (const float*)d_in[4];
    const float* v_shift = (const float*)d_in[5];
    const float* v_scale = (const float*)d_in[6];
    const float* e_shift = (const float*)d_in[7];
    const float* e_scale = (const float*)d_in[8];
    const float* c_W1 = (const float*)d_in[9];
    const float* c_b1 = (const float*)d_in[10];
    const float* c_W2 = (const float*)d_in[11];
    const float* c_b2 = (const float*)d_in[12];
    const float* v_W1 = (const float*)d_in[13];
    const float* v_b1 = (const float*)d_in[14];
    const float* v_W2 = (const float*)d_in[15];
    const float* v_b2 = (const float*)d_in[16];
    const float* vc_Wl  = (const float*)d_in[17];
    const float* vc_bl  = (const float*)d_in[18];
    const float* vc_We  = (const float*)d_in[19];
    const float* vc_Wr  = (const float*)d_in[20];
    const float* vc_sf  = (const float*)d_in[21];
    const float* vc_Wf  = (const float*)d_in[22];
    const float* vc_bf  = (const float*)d_in[23];
    const float* vc_sp  = (const float*)d_in[24];
    const float* vc_Woa = (const float*)d_in[25];
    const float* vc_boa = (const float*)d_in[26];
    const float* vc_Wob = (const float*)d_in[27];
    const float* vc_bob = (const float*)d_in[28];
    const float* cv_Wl  = (const float*)d_in[29];
    const float* cv_bl  = (const float*)d_in[30];
    const float* cv_We  = (const float*)d_in[31];
    const float* cv_Wr  = (const float*)d_in[32];
    const float* cv_sf  = (const float*)d_in[33];
    const float* cv_Wf  = (const float*)d_in[34];
    const float* cv_bf  = (const float*)d_in[35];
    const float* cv_sp  = (const float*)d_in[36];
    const float* cv_Woa = (const float*)d_in[37];
    const float* cv_boa = (const float*)d_in[38];
    const float* cv_Wob = (const float*)d_in[39];
    const float* cv_bob = (const float*)d_in[40];
    const float* out_W1 = (const float*)d_in[41];
    const float* out_b1 = (const float*)d_in[42];
    const float* out_W2 = (const float*)d_in[43];
    const int*   eidx   = (const int*)d_in[44];

    const int NC = in_sizes[0] / 5;
    const int NV = in_sizes[2] / 19;
    const int E  = in_sizes[1];

    // ---- workspace layout (256B aligned slots; R0 layout, items now 4B) ----
    char* ws = (char*)d_ws;
    size_t off = 0;
    auto alloc = [&](size_t bytes) -> size_t {
        size_t o = off;
        off = (off + bytes + 255) & ~(size_t)255;
        return o;
    };
    size_t o_h1 = alloc((size_t)NC * 4);
    size_t o_h2 = alloc((size_t)NV * 4);
    size_t zero_bytes = off;
    size_t o_rs1  = alloc((size_t)(NC + 1) * 4);
    size_t o_rs2  = alloc((size_t)(NV + 1) * 4);
    size_t o_cs1  = alloc(256 * 4);
    size_t o_cs2  = alloc(256 * 4);
    size_t o_p1   = alloc((size_t)E * 4);
    size_t o_p2   = alloc((size_t)E * 4);
    size_t o_G1   = alloc((size_t)NC * 64 * 4);
    size_t o_G2   = alloc((size_t)NV * 64 * 4);  // also hosts rank[E] (u32) early
    size_t o_Emc  = alloc((size_t)NC * 64 * 4);
    size_t o_Emv  = alloc((size_t)NV * 64 * 4);
    size_t o_A1   = alloc((size_t)NC * 64 * 2);  // A2 aliases A1 (dead after agg1)
    size_t o_B1   = alloc((size_t)NV * 64 * 2);
    size_t o_B2   = alloc((size_t)NV * 64 * 2);

    static const int nkt_arr[NMAT] = {1,2,2,1,2,2,2,2,4,2,2,2,4,2,2};
    static const int KR_arr[NMAT]  = {5,64,64,19,64,64,64,64,128,64,64,64,128,64,64};
    const float* src_arr[NMAT] = {c_W1, c_W2, vc_Wl, v_W1, v_W2, vc_Wr, cv_Wr,
                                  vc_Wf, vc_Woa, vc_Wob, cv_Wl,
                                  cv_Wf, cv_Woa, cv_Wob, out_W1};
    size_t o_wh[NMAT], o_wl[NMAT];
    for (int m = 0; m < NMAT; ++m) {
        o_wh[m] = alloc((size_t)nkt_arr[m] * 4 * 64 * 8 * 2);
        o_wl[m] = alloc((size_t)nkt_arr[m] * 4 * 64 * 8 * 2);
    }
    (void)ws_size; (void)n_in; (void)out_size;

    int*  h1   = (int*)(ws + o_h1);
    int*  h2   = (int*)(ws + o_h2);
    int*  rs1  = (int*)(ws + o_rs1);
    int*  rs2  = (int*)(ws + o_rs2);
    int*  cs1  = (int*)(ws + o_cs1);
    int*  cs2  = (int*)(ws + o_cs2);
    unsigned int* rank = (unsigned int*)(ws + o_G2);   // alias: E*4 <= NV*256
    unsigned int* p1 = (unsigned int*)(ws + o_p1);
    unsigned int* p2 = (unsigned int*)(ws + o_p2);
    float* G1  = (float*)(ws + o_G1);
    float* G2  = (float*)(ws + o_G2);
    float* Emc = (float*)(ws + o_Emc);
    float* Emv = (float*)(ws + o_Emv);
    unsigned short* A1 = (unsigned short*)(ws + o_A1);
    unsigned short* B1 = (unsigned short*)(ws + o_B1);
    unsigned short* A2 = (unsigned short*)(ws + o_A1);  // alias
    unsigned short* B2 = (unsigned short*)(ws + o_B2);

    PrepArgs pa;
    for (int m = 0; m < NMAT; ++m) {
        pa.src[m] = src_arr[m];
        pa.hi[m] = (unsigned short*)(ws + o_wh[m]);
        pa.lo[m] = (unsigned short*)(ws + o_wl[m]);
        pa.nkt[m] = nkt_arr[m];
        pa.KR[m] = KR_arr[m];
    }
    auto WH = [&](int m) { return (const unsigned short*)(ws + o_wh[m]); };
    auto WL = [&](int m) { return (const unsigned short*)(ws + o_wl[m]); };

    hipMemsetAsync(ws, 0, zero_bytes, stream);

    // --- weight prep ---
    prep_kernel<<<dim3(4, NMAT), 256, 0, stream>>>(pa);

    // --- fused histogram(+rank) / embeddings ---
    const int tC = (NC + 63) >> 6, tV = (NV + 63) >> 6;
    const int nE = tC + tV;
    FusedArgs fa;
    fa.ei = eidx; fa.E = E; fa.nH = nE;
    fa.h1 = h1; fa.h2 = h2; fa.rank = rank;
    fa.tC = tC; fa.tV = tV;
    fa.cf = cf; fa.NC = NC; fa.c_shift = c_shift; fa.c_scale = c_scale;
    fa.vf = vf; fa.NV = NV; fa.v_shift = v_shift; fa.v_scale = v_scale;
    fa.cW1h = WH(0); fa.cW1l = WL(0); fa.cW2h = WH(1); fa.cW2l = WL(1);
    fa.cWt1h = WH(2); fa.cWt1l = WL(2);
    fa.vW1h = WH(3); fa.vW1l = WL(3); fa.vW2h = WH(4); fa.vW2l = WL(4);
    fa.vWt1h = WH(5); fa.vWt1l = WL(5); fa.vWt2h = WH(6); fa.vWt2l = WL(6);
    fa.c_b1 = c_b1; fa.c_b2 = c_b2; fa.v_b1 = v_b1; fa.v_b2 = v_b2;
    fa.vc_bl = vc_bl; fa.vc_sf = vc_sf; fa.cv_sf = cv_sf;
    fa.Emc = Emc; fa.Emv = Emv; fa.A1 = A1; fa.B1 = B1; fa.B2 = B2;
    fused_he_kernel<<<2 * nE, 256, 0, stream>>>(fa);

    // --- fused scans ---
    const int nch1 = (NC + 4095) / 4096, nch2 = (NV + 4095) / 4096;
    const int nchm = nch1 > nch2 ? nch1 : nch2;
    scanA2_kernel<<<dim3(nchm, 2), 256, 0, stream>>>(h1, NC, cs1, h2, NV, cs2);
    scanB2_kernel<<<2, 256, 0, stream>>>(cs1, nch1, rs1, NC, cs2, nch2, rs2, NV);
    scanC2_kernel<<<dim3(nchm, 2), 256, 0, stream>>>(h1, NC, cs1, rs1, h2, NV, cs2, rs2);

    // --- atomic-free single-pass scatter (4B edge-ids) ---
    scatter_kernel<<<(E + 255) / 256, 256, 0, stream>>>(
        eidx, E, rank, rs1, rs2, p1, p2);
    // rank (G2 slot) dead from here; agg2 overwrites G2 below.

    // --- conv1: target ei0 -> Ttgt=A1, Tsrc=B1, other endpoint = ei1 ---
    agg_kernel<<<(NC + 3) / 4, 256, 0, stream>>>(
        NC, rs1, p1, eidx + E, ef, e_shift, e_scale, A1, B1, vc_We, vc_sf, G1);
    post_mfma<false><<<tC, 256, 0, stream>>>(
        NC, G1, rs1, Emc,
        WH(7), WL(7), vc_bf, vc_sp,
        WH(8), WL(8), vc_boa,
        WH(9), WL(9), vc_bob,
        WH(10), WL(10), cv_bl,
        cv_sf, A2, nullptr, nullptr);

    // --- conv2: target ei1 -> Ttgt=B2, Tsrc=A2, other endpoint = ei0 ---
    agg_kernel<<<(NV + 3) / 4, 256, 0, stream>>>(
        NV, rs2, p2, eidx, ef, e_shift, e_scale, B2, A2, cv_We, cv_sf, G2);
    post_mfma<true><<<tV, 256, 0, stream>>>(
        NV, G2, rs2, Emv,
        WH(11), WL(11), cv_bf, cv_sp,
        WH(12), WL(12), cv_boa,
        WH(13), WL(13), cv_bob,
        WH(14), WL(14), out_b1,
        nullptr, nullptr, out_W2, (float*)d_out);
}